// Round 2
// baseline (1080.179 us; speedup 1.0000x reference)
//
#include <hip/hip_runtime.h>
#include <math.h>

#define NB 256
#define NT 256

// ---------------- ws layout (floats) ----------------
// 64 header (unused) | obs 8192 | hs 65536 | cs 65536 | cur 1024 | prvb 1024
// | emb 32768 | pooled 1048576 | part 524288 | gates 262144   => ~8.04 MB total
#define OFF_OBS    64
#define OFF_HS     8256
#define OFF_CS     73792
#define OFF_CUR    139328
#define OFF_PRVB   140352
#define OFF_EMB    141376
#define OFF_POOLED 174144
#define OFF_PART   1222720
#define OFF_GATES  1747008

// ---------------- init: zero hs/cs + imputation ----------------
__global__ void __launch_bounds__(NT) k_init(const float* __restrict__ observed,
                                             float* __restrict__ obs,
                                             float* __restrict__ hs,
                                             float* __restrict__ cs) {
    int gid = blockIdx.x * NT + threadIdx.x;        // 0..65535
    hs[gid] = 0.f;
    cs[gid] = 0.f;
    if (gid < 512) {
        float vx[8], vy[8];
        int fin = 0;
        for (int tt = 0; tt < 8; tt++) {
            float x = observed[tt * 1024 + gid * 2];
            float y = observed[tt * 1024 + gid * 2 + 1];
            vx[tt] = x; vy[tt] = y;
            if (isfinite(x) && isfinite(y)) fin |= (1 << tt);
        }
        int firstv = -1;
        for (int tt = 7; tt >= 0; tt--) if (fin & (1 << tt)) firstv = tt;
        int last = -1;
        for (int tt = 0; tt < 8; tt++) {
            if (fin & (1 << tt)) last = tt;
            int take = (last >= 0) ? last : firstv;
            float ox = 0.f, oy = 0.f;
            if (take >= 0) { ox = vx[take]; oy = vy[take]; }
            obs[tt * 1024 + gid * 2]     = ox;
            obs[tt * 1024 + gid * 2 + 1] = oy;
        }
    }
}

// ---------------- phase A: social pooling + velocity embedding ----------------
__global__ void __launch_bounds__(NT) k_pool(const float* __restrict__ pos,
                                             const float* __restrict__ prev,
                                             const float* __restrict__ hs,
                                             const float* __restrict__ W_pos,
                                             const float* __restrict__ b_pos,
                                             float* __restrict__ pooled,
                                             float* __restrict__ emb) {
    __shared__ float cell[2][2048];
    __shared__ int   list[2][512];
    __shared__ int   cnt[2];
    const int t = threadIdx.x, b = blockIdx.x;
    const int sub = t >> 7, tl = t & 127;
    const int i = 2 * b + sub;
    if (tl == 0) cnt[sub] = 0;
    __syncthreads();
    float pix = pos[2 * i], piy = pos[2 * i + 1];
    for (int jj = 0; jj < 4; jj++) {
        int j = tl * 4 + jj;
        float dx = pos[2 * j] - pix;
        float dy = pos[2 * j + 1] - piy;
        if (j != i && fabsf(dx) <= 1.0f && fabsf(dy) <= 1.0f) {
            int gx = (int)floorf((dx + 1.0f) * 2.0f); gx = gx < 0 ? 0 : (gx > 3 ? 3 : gx);
            int gy = (int)floorf((dy + 1.0f) * 2.0f); gy = gy < 0 ? 0 : (gy > 3 ? 3 : gy);
            int slot = atomicAdd(&cnt[sub], 1);
            list[sub][slot] = ((gx * 4 + gy) << 16) | j;
        }
    }
    __syncthreads();
    for (int q = tl; q < 2048; q += 128) cell[sub][q] = -__builtin_inff();
    __syncthreads();
    int ne = cnt[sub];
    for (int e = 0; e < ne; e++) {
        int pk = list[sub][e];
        int j = pk & 0xffff, c = pk >> 16;
        float v = hs[j * 128 + tl];
        int a = c * 128 + tl;
        cell[sub][a] = fmaxf(cell[sub][a], v);
    }
    __syncthreads();
    for (int q = tl; q < 2048; q += 128) {
        float v = cell[sub][q];
        pooled[i * 2048 + q] = (v == -__builtin_inff()) ? 0.f : v;
    }
    if (tl < 64) {
        float vx = pix - prev[2 * i];
        float vy = piy - prev[2 * i + 1];
        float e0 = W_pos[tl * 2] * vx + W_pos[tl * 2 + 1] * vy + b_pos[tl];
        emb[i * 64 + tl] = e0 > 0.f ? e0 : 0.f;
    }
}

// ---------------- phase B: soc GEMM K-split partials (32 rowtiles x 8 kchunks) --------
__global__ void __launch_bounds__(NT) k_socgemm(const float* __restrict__ pooled,
                                                const float* __restrict__ W_pool,
                                                float* __restrict__ part) {
    __shared__ float As[16 * 264];
    __shared__ float Ws[128 * 36];
    const int t = threadIdx.x, b = blockIdx.x;
    const int kc = b & 7, rt = b >> 3;
    const int R0 = rt * 16;
    const float4* P4 = (const float4*)pooled;
    for (int jj = 0; jj < 4; jj++) {
        int idx = jj * NT + t;              // 0..1023
        int r = idx >> 6, k4 = idx & 63;
        float4 v = P4[(R0 + r) * 512 + kc * 64 + k4];
        *(float4*)&As[r * 264 + k4 * 4] = v;
    }
    const int pg = t & 63, rg = t >> 6;
    float acc[4][2] = {{0.f,0.f},{0.f,0.f},{0.f,0.f},{0.f,0.f}};
    const float4* W4 = (const float4*)W_pool;
    for (int ss = 0; ss < 8; ss++) {
        __syncthreads();
        for (int jj = 0; jj < 4; jj++) {
            int idx = jj * NT + t;          // 0..1023
            int p = idx >> 3, k4 = idx & 7;
            float4 v = W4[p * 512 + kc * 64 + ss * 8 + k4];
            *(float4*)&Ws[p * 36 + k4 * 4] = v;
        }
        __syncthreads();
        #pragma unroll
        for (int k4 = 0; k4 < 8; k4++) {
            float4 w0 = *(const float4*)&Ws[pg * 36 + k4 * 4];
            float4 w1 = *(const float4*)&Ws[(pg + 64) * 36 + k4 * 4];
            #pragma unroll
            for (int r = 0; r < 4; r++) {
                float4 a = *(const float4*)&As[(rg * 4 + r) * 264 + ss * 32 + k4 * 4];
                acc[r][0] += a.x * w0.x + a.y * w0.y + a.z * w0.z + a.w * w0.w;
                acc[r][1] += a.x * w1.x + a.y * w1.y + a.z * w1.z + a.w * w1.w;
            }
        }
    }
    for (int r = 0; r < 4; r++) {
        int row = R0 + rg * 4 + r;
        part[(kc * 512 + row) * 128 + pg]      = acc[r][0];
        part[(kc * 512 + row) * 128 + pg + 64] = acc[r][1];
    }
}

// ---------------- phase C: gates GEMM (32 rowtiles x 8 outchunks, K=320) ----------------
__global__ void __launch_bounds__(NT) k_gates(const float* __restrict__ emb,
                                              const float* __restrict__ part,
                                              const float* __restrict__ hs,
                                              const float* __restrict__ b_pool,
                                              const float* __restrict__ W_ih,
                                              const float* __restrict__ b_ih,
                                              const float* __restrict__ W_hh,
                                              const float* __restrict__ b_hh,
                                              float* __restrict__ gates) {
    __shared__ float As[16 * 324];
    __shared__ float Ws[64 * 36];
    const int t = threadIdx.x, b = blockIdx.x;
    const int oc = b & 7, rt = b >> 3;
    const int R0 = rt * 16, O0 = oc * 64;
    const float4* E4  = (const float4*)emb;
    const float4* Pp4 = (const float4*)part;
    const float4* H4  = (const float4*)hs;
    const float4* B4  = (const float4*)b_pool;
    // stage x = [emb | soc | hs]; soc = reduce_k(partials) + bias, relu
    {
        int r = t >> 4, k4 = t & 15;
        *(float4*)&As[r * 324 + k4 * 4] = E4[(R0 + r) * 16 + k4];
    }
    for (int jj = 0; jj < 2; jj++) {
        int idx = jj * NT + t;              // 0..511
        int r = idx >> 5, k4 = idx & 31;
        float4 sum = Pp4[(R0 + r) * 32 + k4];
        for (int kc = 1; kc < 8; kc++) {
            float4 v = Pp4[(kc * 512 + R0 + r) * 32 + k4];
            sum.x += v.x; sum.y += v.y; sum.z += v.z; sum.w += v.w;
        }
        float4 bb = B4[k4];
        sum.x = fmaxf(sum.x + bb.x, 0.f);
        sum.y = fmaxf(sum.y + bb.y, 0.f);
        sum.z = fmaxf(sum.z + bb.z, 0.f);
        sum.w = fmaxf(sum.w + bb.w, 0.f);
        *(float4*)&As[r * 324 + 64 + k4 * 4] = sum;
    }
    for (int jj = 0; jj < 2; jj++) {
        int idx = jj * NT + t;
        int r = idx >> 5, k4 = idx & 31;
        *(float4*)&As[r * 324 + 192 + k4 * 4] = H4[(R0 + r) * 32 + k4];
    }
    const int ol = t & 63, rg = t >> 6;
    const float4* Wi4 = (const float4*)W_ih;
    const float4* Wh4 = (const float4*)W_hh;
    float acc[4] = {0.f, 0.f, 0.f, 0.f};
    for (int ss = 0; ss < 10; ss++) {
        __syncthreads();
        for (int jj = 0; jj < 2; jj++) {
            int idx = jj * NT + t;          // 0..511
            int o = idx >> 3, k4 = idx & 7;
            float4 v = (ss < 6) ? Wi4[(O0 + o) * 48 + ss * 8 + k4]
                                : Wh4[(O0 + o) * 32 + (ss - 6) * 8 + k4];
            *(float4*)&Ws[o * 36 + k4 * 4] = v;
        }
        __syncthreads();
        #pragma unroll
        for (int k4 = 0; k4 < 8; k4++) {
            float4 w = *(const float4*)&Ws[ol * 36 + k4 * 4];
            #pragma unroll
            for (int r = 0; r < 4; r++) {
                float4 a = *(const float4*)&As[(rg * 4 + r) * 324 + ss * 32 + k4 * 4];
                acc[r] += a.x * w.x + a.y * w.y + a.z * w.z + a.w * w.w;
            }
        }
    }
    float bias = b_ih[O0 + ol] + b_hh[O0 + ol];
    for (int r = 0; r < 4; r++)
        gates[(R0 + rg * 4 + r) * 512 + O0 + ol] = acc[r] + bias;
}

// ---------------- phase D: pointwise LSTM + position update ----------------
__global__ void __launch_bounds__(NT) k_point(const float* __restrict__ gates,
                                              float* __restrict__ cs,
                                              float* __restrict__ hs,
                                              const float* __restrict__ W_out,
                                              const float* __restrict__ b_out,
                                              const float* __restrict__ pos,
                                              float* __restrict__ cur,
                                              float* __restrict__ prvb,
                                              float* __restrict__ out,
                                              int s) {
    __shared__ float red[16];
    const int t = threadIdx.x, b = blockIdx.x;
    const int sub = t >> 7, tl = t & 127;
    const int i = 2 * b + sub;
    float gi = gates[i * 512 + tl];
    float gf = gates[i * 512 + 128 + tl];
    float gg = gates[i * 512 + 256 + tl];
    float go = gates[i * 512 + 384 + tl];
    float co = cs[i * 128 + tl];
    float si = 1.f / (1.f + expf(-gi));
    float sf = 1.f / (1.f + expf(-gf));
    float so = 1.f / (1.f + expf(-go));
    float c2 = sf * co + si * tanhf(gg);
    float h2 = so * tanhf(c2);
    cs[i * 128 + tl] = c2;
    hs[i * 128 + tl] = h2;
    float o0 = W_out[tl] * h2;
    float o1 = W_out[128 + tl] * h2;
    for (int off = 32; off; off >>= 1) {
        o0 += __shfl_down(o0, off);
        o1 += __shfl_down(o1, off);
    }
    int wid = t >> 6;
    if ((t & 63) == 0) { red[wid * 2] = o0; red[wid * 2 + 1] = o1; }
    __syncthreads();
    if (tl == 0) {
        float px = pos[2 * i], py = pos[2 * i + 1];
        float nx = px + b_out[0] + red[sub * 4]     + red[sub * 4 + 2];
        float ny = py + b_out[1] + red[sub * 4 + 1] + red[sub * 4 + 3];
        if (s == 6) {
            cur[2 * i] = px; cur[2 * i + 1] = py;
            prvb[2 * i] = px; prvb[2 * i + 1] = py;
        } else if (s >= 7) {
            out[(s - 7) * 1024 + 2 * i]     = nx;
            out[(s - 7) * 1024 + 2 * i + 1] = ny;
            prvb[2 * i] = px; prvb[2 * i + 1] = py;
            cur[2 * i] = nx; cur[2 * i + 1] = ny;
        }
    }
}

extern "C" void kernel_launch(void* const* d_in, const int* in_sizes, int n_in,
                              void* d_out, int out_size, void* d_ws, size_t ws_size,
                              hipStream_t stream) {
    const float* observed = (const float*)d_in[0];
    const float* W_pos    = (const float*)d_in[1];
    const float* b_pos    = (const float*)d_in[2];
    const float* W_pool   = (const float*)d_in[3];
    const float* b_pool   = (const float*)d_in[4];
    const float* Wih_e    = (const float*)d_in[5];
    const float* bih_e    = (const float*)d_in[6];
    const float* Whh_e    = (const float*)d_in[7];
    const float* bhh_e    = (const float*)d_in[8];
    const float* Wih_d    = (const float*)d_in[9];
    const float* bih_d    = (const float*)d_in[10];
    const float* Whh_d    = (const float*)d_in[11];
    const float* bhh_d    = (const float*)d_in[12];
    const float* W_out    = (const float*)d_in[13];
    const float* b_out    = (const float*)d_in[14];
    float* outp = (float*)d_out;
    float* w    = (float*)d_ws;

    float* obs    = w + OFF_OBS;
    float* hs     = w + OFF_HS;
    float* cs     = w + OFF_CS;
    float* cur    = w + OFF_CUR;
    float* prvb   = w + OFF_PRVB;
    float* emb    = w + OFF_EMB;
    float* pooled = w + OFF_POOLED;
    float* part   = w + OFF_PART;
    float* gates  = w + OFF_GATES;

    int npred = out_size / 1024;   // out_size = npred*512*2
    int nstep = 7 + npred;

    k_init<<<NB, NT, 0, stream>>>(observed, obs, hs, cs);

    for (int s = 0; s < nstep; s++) {
        const float* pos  = (s < 7) ? (obs + (s + 1) * 1024) : cur;
        const float* prev = (s < 7) ? (obs + s * 1024) : prvb;
        const float* W_ih = (s < 7) ? Wih_e : Wih_d;
        const float* b_ih = (s < 7) ? bih_e : bih_d;
        const float* W_hh = (s < 7) ? Whh_e : Whh_d;
        const float* b_hh = (s < 7) ? bhh_e : bhh_d;

        k_pool   <<<NB, NT, 0, stream>>>(pos, prev, hs, W_pos, b_pos, pooled, emb);
        k_socgemm<<<NB, NT, 0, stream>>>(pooled, W_pool, part);
        k_gates  <<<NB, NT, 0, stream>>>(emb, part, hs, b_pool, W_ih, b_ih, W_hh, b_hh, gates);
        k_point  <<<NB, NT, 0, stream>>>(gates, cs, hs, W_out, b_out, pos, cur, prvb, outp, s);
    }
}